// Round 2
// baseline (444.964 us; speedup 1.0000x reference)
//
#include <hip/hip_runtime.h>

// CalcSpixelFeats R21. Base = R20 (112.0us, neutral vs R19 109.6).
// STRUCTURAL REWRITE: the materialize-then-scan pipeline (prep->recs->scan)
// is replaced by ONE fused kernel. K=256 bins x 33 floats = 33.8 KB fits in
// LDS, so each block scatter-reduces its 512 pixels directly into a per-block
// bin table via ds_add_f32, then flushes with fire-and-forget global fp
// atomics. Eliminates: 25 MB record write + 25 MB gather, ids/cnt machinery,
// the rank-reservation chain, one kernel launch+drain, and the bf16 pack
// (full f32 precision now).
// Bin stride = 33 (ODD) on purpose: bank = (33*bin + c) & 31 = (bin + c) & 31
// -> random bins spread over all 32 banks. Stride 34 would give
// (2*bin + c) & 31 -> only 16 banks reachable per parity -> 4-way conflicts.

#define CCH  32         // channels, fixed by problem
#define TPB  512        // 1 px/thread, 2 blocks/CU -> 16 waves/CU
#define KMAX 256        // superpixel count, fixed by problem
#define BSTR 33         // bin stride in floats (32 ch + wsum), odd for banks

__global__ __launch_bounds__(TPB, 4) void spx_fused_kernel(
    const float* __restrict__ pf,      // [B][C][P]
    const float* __restrict__ assoc,   // [B][9][P]
    const int*   __restrict__ idxmap,  // [B][P]
    const int*   __restrict__ nw_p,
    const int*   __restrict__ nh_p,
    float*       __restrict__ fsum,    // [B*K][CCH+1]
    int P, int K, int bpb)             // bpb = P / TPB
{
    __shared__ float bins[KMAX * BSTR];   // 33.8 KB

    const int b   = blockIdx.x / bpb;
    const int blk = blockIdx.x - b * bpb;
    const int tid = threadIdx.x;
    const int p   = blk * TPB + tid;   // pixel within batch (1 px/thread)

    // zero the bin table (17 floats/thread)
    for (int i = tid; i < KMAX * BSTR; i += TPB) bins[i] = 0.f;

    const int*   ix_b = idxmap + (size_t)b * P;
    const float* pf_b = pf     + (size_t)b * CCH * P;
    const float* as_b = assoc  + (size_t)b * 9 * P;

    // coalesced loads, all independent -> deep MLP while bins zero
    const int idx = ix_b[p];
    float f[CCH];
#pragma unroll
    for (int c = 0; c < CCH; ++c) f[c] = pf_b[(size_t)c * P + p];
    float wv[9];
#pragma unroll
    for (int j = 0; j < 9; ++j) wv[j] = as_b[(size_t)j * P + p];

    const int nw = nw_p[0], nh = nh_p[0];
    const int iy  = idx / nw;
    const int ixx = idx - iy * nw;

    __syncthreads();   // bins zeroed before any ds_add

#pragma unroll
    for (int j = 0; j < 9; ++j) {
        const int ty = iy + j / 3 - 1;
        const int tx = ixx + j % 3 - 1;
        if (tx < 0 || tx >= nw || ty < 0 || ty >= nh) continue;
        float* bb = &bins[(ty * nw + tx) * BSTR];
        const float w = wv[j];
        atomicAdd(&bb[CCH], w);               // ds_add_f32, no return
#pragma unroll
        for (int c = 0; c < CCH; ++c)
            atomicAdd(&bb[c], w * f[c]);      // imm-offset ds_add_f32
    }

    __syncthreads();

    // flush block partials: 256 bins x 33 cols, consecutive addresses per
    // thread-stride -> coalesced fire-and-forget global fp atomics
    float* fs_b = fsum + (size_t)b * K * (CCH + 1);
    for (int i = tid; i < KMAX * (CCH + 1); i += TPB) {
        const int bin = i / (CCH + 1);
        const int cc  = i - bin * (CCH + 1);
        unsafeAtomicAdd(&fs_b[bin * (CCH + 1) + cc], bins[bin * BSTR + cc]);
    }
}

// Trivial finalize: one thread per output element (b,c,k), k fastest ->
// coalesced writes; fsum reads hit L2 (135 KB). Separate dispatch gives the
// device-wide visibility barrier for the atomics (kernel-boundary coherence).
__global__ __launch_bounds__(256) void spx_finalize_kernel(
    const float* __restrict__ fsum,  // [B*K][CCH+1]
    float*       __restrict__ out,   // [B][C][K]
    int K, int total)
{
    const int gid = blockIdx.x * 256 + threadIdx.x;
    if (gid >= total) return;
    const int k = gid % K;
    const int c = (gid / K) % CCH;
    const int b = gid / (K * CCH);
    const float* f = fsum + (size_t)(b * K + k) * (CCH + 1);
    const float W = f[CCH];
    out[gid] = (W > 1e-16f) ? (f[c] / W) : 0.f;
}

extern "C" void kernel_launch(void* const* d_in, const int* in_sizes, int n_in,
                              void* d_out, int out_size, void* d_ws, size_t ws_size,
                              hipStream_t stream) {
    const float* pf     = (const float*)d_in[0];
    const float* assoc  = (const float*)d_in[1];
    const int*   idxmap = (const int*)d_in[2];
    const int*   nw_p   = (const int*)d_in[3];
    const int*   nh_p   = (const int*)d_in[4];
    float* out = (float*)d_out;

    const int BP = in_sizes[2];          // B*P = 262144
    const int B  = 4;                    // fixed by reference setup
    const int P  = BP / B;               // 65536
    const int K  = out_size / (B * CCH); // 256 (== KMAX)

    // ws: fsum [B*K][33] only — records/ids/cnt machinery is gone
    const size_t fsum_bytes = (size_t)B * K * (CCH + 1) * sizeof(float);
    float* fsum = (float*)d_ws;

    hipMemsetAsync(fsum, 0, fsum_bytes, stream);

    const int bpb = P / TPB;             // 128 blocks per batch
    spx_fused_kernel<<<B * bpb, TPB, 0, stream>>>(
        pf, assoc, idxmap, nw_p, nh_p, fsum, P, K, bpb);

    const int total = B * K * CCH;
    spx_finalize_kernel<<<(total + 255) / 256, 256, 0, stream>>>(
        fsum, out, K, total);
}